// Round 8
// baseline (437.536 us; speedup 1.0000x reference)
//
#include <hip/hip_runtime.h>
#include <stdint.h>

// B=32, CH=64, T=2048. float32 in/out per the reference.
#define BB 32
#define CHN 64
#define TT 2048
#define LOG2E 1.4426950408889634f

typedef __attribute__((ext_vector_type(8))) short short8;
typedef __attribute__((ext_vector_type(4))) float f32x4;

#if defined(__has_builtin)
#if __has_builtin(__builtin_amdgcn_exp2f)
#define EXP2F __builtin_amdgcn_exp2f
#else
#define EXP2F exp2f
#endif
#else
#define EXP2F exp2f
#endif

// HW packed f32->bf16 (RNE), src0 -> low half, src1 -> high half.
__device__ __forceinline__ unsigned int pkbf(float a, float b) {
    unsigned int d;
    asm("v_cvt_pk_bf16_f32 %0, %1, %2" : "=v"(d) : "v"(a), "v"(b));
    return d;
}

__device__ __forceinline__ short8 cvt8(float4 q0, float4 q1) {
    union { unsigned int u[4]; short8 s; } v;
    v.u[0] = pkbf(q0.x, q0.y);
    v.u[1] = pkbf(q0.z, q0.w);
    v.u[2] = pkbf(q1.x, q1.y);
    v.u[3] = pkbf(q1.z, q1.w);
    return v.s;
}

// Transpose-staging swizzle for prep's LDS tile, element (t, c) -> short idx.
__device__ __forceinline__ int jt_idx(int t, int c) {
    int sw = ((t & 7) ^ ((t >> 3) & 7)) << 3;
    return t * 64 + (c ^ sw);
}

// Per-wave 16x64 P tile, (row=i-local, col=t-local) -> short idx (LDS).
__device__ __forceinline__ int pl_idx(int r, int c) {
    return r * 64 + (c ^ ((r & 7) << 3));
}

// ---------------------------------------------------------------------------
// Prep: one (b, 64-t chunk) per block.  Plain row-major bf16 chunk tiles:
//   XtS[b][ch]: [t-local 0..64)[c 0..64)   (Gram A/B fragments)
//   XnS[b][ch]: [c 0..64)[t-local 0..64)   (PV B fragments)
// b = blockIdx&31 keeps each batch's tiles on one XCD's L2 (round 6 win).
// ---------------------------------------------------------------------------
__global__ __launch_bounds__(256) void prep_kernel(
        const float* __restrict__ x,
        unsigned short* __restrict__ XtS,
        unsigned short* __restrict__ XnS) {
    __shared__ unsigned short Jt[64 * 64];
    int tid = threadIdx.x;
    int b  = blockIdx.x & 31;
    int ch = blockIdx.x >> 5;
    int t0 = ch * 64;
    const float* xb = x + (size_t)b * CHN * TT;
    unsigned short* xt_blk = XtS + (size_t)(b * 32 + ch) * 4096;
    unsigned short* xn_blk = XnS + (size_t)(b * 32 + ch) * 4096;

    int p = tid >> 3;              // c rows 2p, 2p+1
    int tsub = (tid & 7) * 8;      // 8 t per thread
    int r0 = 2 * p, r1 = 2 * p + 1;
    const float* s0 = xb + (size_t)r0 * TT + t0 + tsub;
    const float* s1 = s0 + TT;
    float4 qa = *(const float4*)s0, qb = *(const float4*)(s0 + 4);
    float4 qc = *(const float4*)s1, qd = *(const float4*)(s1 + 4);
    short8 v0 = cvt8(qa, qb);
    short8 v1 = cvt8(qc, qd);

    // XnS rows (plain)
    *(short8*)(xn_blk + (size_t)r0 * 64 + tsub) = v0;
    *(short8*)(xn_blk + (size_t)r1 * 64 + tsub) = v1;

    // transpose via LDS (packed c-pairs, swizzled against bank conflicts)
#pragma unroll
    for (int j = 0; j < 8; ++j) {
        int t = tsub + j;
        unsigned int pack = ((unsigned int)(unsigned short)v0[j]) |
                            (((unsigned int)(unsigned short)v1[j]) << 16);
        *(unsigned int*)&Jt[jt_idx(t, r0)] = pack;
    }
    __syncthreads();

    // XtS rows (plain): t = tid>>2, 16-c segment e = tid&3
    int t = tid >> 2, e = tid & 3;
    short8 w0 = *(const short8*)&Jt[jt_idx(t, e * 16)];
    short8 w1 = *(const short8*)&Jt[jt_idx(t, e * 16 + 8)];
    unsigned short* dst = xt_blk + (size_t)t * 64 + e * 16;
    *(short8*)dst = w0;
    *(short8*)(dst + 8) = w1;
}

// ---------------------------------------------------------------------------
// Attn: block = (b, 64 i-rows), b = blockIdx&31 (XCD affinity).
// NO __syncthreads, NO LDS staging: fragments load directly from the
// L2-resident XtS/XnS (plain layout, wave-coalesced b128).  LDS holds only
// the 1KB wave-private P tile.  8 blocks/CU -> TLP hides L2 latency.
// ---------------------------------------------------------------------------
__global__ __launch_bounds__(256, 8) void attn_kernel(
        const unsigned short* __restrict__ XtS,
        const unsigned short* __restrict__ XnS,
        const float* __restrict__ x,
        const float* __restrict__ w1,
        const float* __restrict__ w2,
        const float* __restrict__ gptr,
        float* __restrict__ out) {
    __shared__ unsigned short Pl[4][1024];    // 8 KB total, wave-private

    int tid  = threadIdx.x;
    int b    = blockIdx.x & 31;
    int iblk = blockIdx.x >> 5;
    int wave = tid >> 6, lane = tid & 63;
    int quad = lane >> 4, l15 = lane & 15;
    int i0 = iblk * 64;

    const unsigned short* XtB = XtS + (size_t)b * 32 * 4096;
    const unsigned short* XnB = XnS + (size_t)b * 32 * 4096;
    const float* xb = x + (size_t)b * CHN * TT;

    float s11 = 0.f;
#pragma unroll
    for (int h = 0; h < 8; ++h) s11 += w1[h] * w2[h];

    // A fragments: rows i0 + wave*16 + l15, direct from XtS
    const unsigned short* arow = XtB + (size_t)iblk * 4096 +
                                 (size_t)(wave * 16 + l15) * 64 + quad * 8;
    short8 a0 = *(const short8*)arow;
    short8 a1 = *(const short8*)(arow + 32);

    // ---- Phase 1: raw-Gram row min/max ----
    float vmin[4], vmax[4];
#pragma unroll
    for (int r = 0; r < 4; ++r) { vmin[r] = 3.4e38f; vmax[r] = -3.4e38f; }

    const unsigned short* fb = XtB + (size_t)l15 * 64 + quad * 8;
    for (int m = 0; m < 32; ++m) {
        const unsigned short* tp = fb + (size_t)m * 4096;
#pragma unroll
        for (int sub = 0; sub < 4; ++sub) {
            const unsigned short* brow = tp + (size_t)sub * (16 * 64);
            short8 b0 = *(const short8*)brow;
            short8 b1 = *(const short8*)(brow + 32);
            f32x4 acc = {0.f, 0.f, 0.f, 0.f};
            acc = __builtin_amdgcn_mfma_f32_16x16x32_bf16(a0, b0, acc, 0, 0, 0);
            acc = __builtin_amdgcn_mfma_f32_16x16x32_bf16(a1, b1, acc, 0, 0, 0);
#pragma unroll
            for (int r = 0; r < 4; ++r) {
                vmin[r] = fminf(vmin[r], acc[r]);
                vmax[r] = fmaxf(vmax[r], acc[r]);
            }
        }
    }
#pragma unroll
    for (int m = 1; m <= 8; m <<= 1) {
#pragma unroll
        for (int r = 0; r < 4; ++r) {
            vmin[r] = fminf(vmin[r], __shfl_xor(vmin[r], m));
            vmax[r] = fmaxf(vmax[r], __shfl_xor(vmax[r], m));
        }
    }
    float rdl2[4], mlog[4];
#pragma unroll
    for (int r = 0; r < 4; ++r) {
        float e0 = s11 * vmin[r], e1 = s11 * vmax[r];
        float mn = fminf(e0, e1), mx = fmaxf(e0, e1);
        float rd = LOG2E / (mx - mn + 1e-8f);
        rdl2[r] = s11 * rd;      // applied to raw Gram acc
        mlog[r] = mn * rd;
    }

    // ---- Phase 2: P = exp2(acc*rdl2 - mlog) -> (LDS turn) -> PV ----
    f32x4 oacc[4];
#pragma unroll
    for (int g = 0; g < 4; ++g) oacc[g] = (f32x4){0.f, 0.f, 0.f, 0.f};
    float lsum[4] = {0.f, 0.f, 0.f, 0.f};
    unsigned short* Pw = &Pl[wave][0];

    const unsigned short* nb = XnB + (size_t)l15 * 64 + quad * 8;
    for (int m = 0; m < 32; ++m) {
        const unsigned short* tp = fb + (size_t)m * 4096;
        const unsigned short* xn = nb + (size_t)m * 4096;
#pragma unroll
        for (int sub = 0; sub < 4; ++sub) {
            const unsigned short* brow = tp + (size_t)sub * (16 * 64);
            short8 b0 = *(const short8*)brow;
            short8 b1 = *(const short8*)(brow + 32);
            f32x4 acc = {0.f, 0.f, 0.f, 0.f};
            acc = __builtin_amdgcn_mfma_f32_16x16x32_bf16(a0, b0, acc, 0, 0, 0);
            acc = __builtin_amdgcn_mfma_f32_16x16x32_bf16(a1, b1, acc, 0, 0, 0);
            float pv0 = EXP2F(fmaf(acc[0], rdl2[0], -mlog[0]));
            float pv1 = EXP2F(fmaf(acc[1], rdl2[1], -mlog[1]));
            float pv2 = EXP2F(fmaf(acc[2], rdl2[2], -mlog[2]));
            float pv3 = EXP2F(fmaf(acc[3], rdl2[3], -mlog[3]));
            lsum[0] += pv0; lsum[1] += pv1; lsum[2] += pv2; lsum[3] += pv3;
            unsigned int k01 = pkbf(pv0, pv1);
            unsigned int k23 = pkbf(pv2, pv3);
            Pw[pl_idx(quad * 4 + 0, sub * 16 + l15)] = (unsigned short)k01;
            Pw[pl_idx(quad * 4 + 1, sub * 16 + l15)] = (unsigned short)(k01 >> 16);
            Pw[pl_idx(quad * 4 + 2, sub * 16 + l15)] = (unsigned short)k23;
            Pw[pl_idx(quad * 4 + 3, sub * 16 + l15)] = (unsigned short)(k23 >> 16);
        }
        // own-wave DS ordering (P slice is wave-private; DS retires in-order)
        asm volatile("s_waitcnt lgkmcnt(0)" ::: "memory");
        short8 pf0 = *(const short8*)&Pw[pl_idx(l15, quad * 8)];
        short8 pf1 = *(const short8*)&Pw[pl_idx(l15, 32 + quad * 8)];
#pragma unroll
        for (int g = 0; g < 4; ++g) {
            const unsigned short* vr = xn + (size_t)g * (16 * 64);
            short8 bv0 = *(const short8*)vr;
            short8 bv1 = *(const short8*)(vr + 32);
            oacc[g] = __builtin_amdgcn_mfma_f32_16x16x32_bf16(pf0, bv0, oacc[g], 0, 0, 0);
            oacc[g] = __builtin_amdgcn_mfma_f32_16x16x32_bf16(pf1, bv1, oacc[g], 0, 0, 0);
        }
    }

    // ---- Epilogue ----
#pragma unroll
    for (int m = 1; m <= 8; m <<= 1) {
#pragma unroll
        for (int r = 0; r < 4; ++r) lsum[r] += __shfl_xor(lsum[r], m);
    }
    float gamma = gptr[0];
    float rl[4];
#pragma unroll
    for (int r = 0; r < 4; ++r) rl[r] = gamma / lsum[r];

    int ibase = i0 + wave * 16 + quad * 4;
#pragma unroll
    for (int g = 0; g < 4; ++g) {
        int c = g * 16 + l15;
        float4 xv = *(const float4*)(xb + (size_t)c * TT + ibase);
        float4 ov;
        ov.x = fmaf(oacc[g][0], rl[0], xv.x);
        ov.y = fmaf(oacc[g][1], rl[1], xv.y);
        ov.z = fmaf(oacc[g][2], rl[2], xv.z);
        ov.w = fmaf(oacc[g][3], rl[3], xv.w);
        *(float4*)(out + ((size_t)b * CHN + c) * TT + ibase) = ov;
    }
}

// ---------------------------------------------------------------------------
// Fallback (round-3 structure, zero workspace) — only if ws < 16 MB.
// ---------------------------------------------------------------------------
__device__ __forceinline__ void stage_tile_fb(const float* __restrict__ xb,
                                              int tbase, unsigned short* Jt, int tid) {
    int p = tid >> 3;
    int tsub = (tid & 7) * 8;
    const float* s0 = xb + (size_t)(2 * p) * TT + tbase + tsub;
    const float* s1 = s0 + TT;
    float4 a0 = *(const float4*)s0;
    float4 a1 = *(const float4*)(s0 + 4);
    float4 b0 = *(const float4*)s1;
    float4 b1 = *(const float4*)(s1 + 4);
    short8 v0 = cvt8(a0, a1);
    short8 v1 = cvt8(b0, b1);
#pragma unroll
    for (int j = 0; j < 8; ++j) {
        int t = tsub + j;
        unsigned int pack = ((unsigned int)(unsigned short)v0[j]) |
                            (((unsigned int)(unsigned short)v1[j]) << 16);
        *(unsigned int*)&Jt[jt_idx(t, 2 * p)] = pack;
    }
}

__global__ __launch_bounds__(256) void fused_attn_fallback(
        const float* __restrict__ x,
        const float* __restrict__ w1,
        const float* __restrict__ w2,
        const float* __restrict__ gptr,
        float* __restrict__ out) {
    __shared__ unsigned short Jt[64 * 64];
    __shared__ unsigned short Pl[4][16 * 64];

    int tid  = threadIdx.x;
    int b    = blockIdx.x >> 5;
    int iblk = blockIdx.x & 31;
    int wave = tid >> 6;
    int lane = tid & 63;
    int quad = lane >> 4, l15 = lane & 15;
    int i0 = iblk * 64;
    const float* xb = x + (size_t)b * CHN * TT;

    float s11 = 0.f;
#pragma unroll
    for (int h = 0; h < 8; ++h) s11 += w1[h] * w2[h];

    stage_tile_fb(xb, i0, Jt, tid);
    __syncthreads();
    short8 a0 = *(const short8*)&Jt[jt_idx(wave * 16 + l15, quad * 8)];
    short8 a1 = *(const short8*)&Jt[jt_idx(wave * 16 + l15, 32 + quad * 8)];

    float vmin[4], vmax[4];
#pragma unroll
    for (int r = 0; r < 4; ++r) { vmin[r] = 3.4e38f; vmax[r] = -3.4e38f; }

    for (int t0 = 0; t0 < TT; t0 += 64) {
        __syncthreads();
        stage_tile_fb(xb, t0, Jt, tid);
        __syncthreads();
#pragma unroll
        for (int sub = 0; sub < 4; ++sub) {
            short8 b0 = *(const short8*)&Jt[jt_idx(sub * 16 + l15, quad * 8)];
            short8 b1 = *(const short8*)&Jt[jt_idx(sub * 16 + l15, 32 + quad * 8)];
            f32x4 acc = {0.f, 0.f, 0.f, 0.f};
            acc = __builtin_amdgcn_mfma_f32_16x16x32_bf16(a0, b0, acc, 0, 0, 0);
            acc = __builtin_amdgcn_mfma_f32_16x16x32_bf16(a1, b1, acc, 0, 0, 0);
#pragma unroll
            for (int r = 0; r < 4; ++r) {
                vmin[r] = fminf(vmin[r], acc[r]);
                vmax[r] = fmaxf(vmax[r], acc[r]);
            }
        }
    }
#pragma unroll
    for (int m = 1; m <= 8; m <<= 1) {
#pragma unroll
        for (int r = 0; r < 4; ++r) {
            vmin[r] = fminf(vmin[r], __shfl_xor(vmin[r], m));
            vmax[r] = fmaxf(vmax[r], __shfl_xor(vmax[r], m));
        }
    }
    float rdl2[4], mlog[4];
#pragma unroll
    for (int r = 0; r < 4; ++r) {
        float e0 = s11 * vmin[r], e1 = s11 * vmax[r];
        float mn = fminf(e0, e1), mx = fmaxf(e0, e1);
        float rd = LOG2E / (mx - mn + 1e-8f);
        rdl2[r] = s11 * rd;
        mlog[r] = mn * rd;
    }

    f32x4 oacc[4];
#pragma unroll
    for (int g = 0; g < 4; ++g) oacc[g] = (f32x4){0.f, 0.f, 0.f, 0.f};
    float lsum[4] = {0.f, 0.f, 0.f, 0.f};
    unsigned short* Pw = &Pl[wave][0];

    for (int t0 = 0; t0 < TT; t0 += 64) {
        __syncthreads();
        stage_tile_fb(xb, t0, Jt, tid);
        __syncthreads();
#pragma unroll
        for (int sub = 0; sub < 4; ++sub) {
            short8 b0 = *(const short8*)&Jt[jt_idx(sub * 16 + l15, quad * 8)];
            short8 b1 = *(const short8*)&Jt[jt_idx(sub * 16 + l15, 32 + quad * 8)];
            f32x4 acc = {0.f, 0.f, 0.f, 0.f};
            acc = __builtin_amdgcn_mfma_f32_16x16x32_bf16(a0, b0, acc, 0, 0, 0);
            acc = __builtin_amdgcn_mfma_f32_16x16x32_bf16(a1, b1, acc, 0, 0, 0);
            float pv0 = EXP2F(fmaf(acc[0], rdl2[0], -mlog[0]));
            float pv1 = EXP2F(fmaf(acc[1], rdl2[1], -mlog[1]));
            float pv2 = EXP2F(fmaf(acc[2], rdl2[2], -mlog[2]));
            float pv3 = EXP2F(fmaf(acc[3], rdl2[3], -mlog[3]));
            lsum[0] += pv0; lsum[1] += pv1; lsum[2] += pv2; lsum[3] += pv3;
            unsigned int k01 = pkbf(pv0, pv1);
            unsigned int k23 = pkbf(pv2, pv3);
            Pw[pl_idx(quad * 4 + 0, sub * 16 + l15)] = (unsigned short)k01;
            Pw[pl_idx(quad * 4 + 1, sub * 16 + l15)] = (unsigned short)(k01 >> 16);
            Pw[pl_idx(quad * 4 + 2, sub * 16 + l15)] = (unsigned short)k23;
            Pw[pl_idx(quad * 4 + 3, sub * 16 + l15)] = (unsigned short)(k23 >> 16);
        }
        asm volatile("s_waitcnt lgkmcnt(0)" ::: "memory");
        short8 pf0 = *(const short8*)&Pw[pl_idx(l15, quad * 8)];
        short8 pf1 = *(const short8*)&Pw[pl_idx(l15, 32 + quad * 8)];
#pragma unroll
        for (int g = 0; g < 4; ++g) {
            const float* vr = xb + (size_t)(g * 16 + l15) * TT + t0;
            float4 q0 = *(const float4*)(vr + quad * 8);
            float4 q1 = *(const float4*)(vr + quad * 8 + 4);
            float4 q2 = *(const float4*)(vr + 32 + quad * 8);
            float4 q3 = *(const float4*)(vr + 32 + quad * 8 + 4);
            short8 bv0 = cvt8(q0, q1);
            short8 bv1 = cvt8(q2, q3);
            oacc[g] = __builtin_amdgcn_mfma_f32_16x16x32_bf16(pf0, bv0, oacc[g], 0, 0, 0);
            oacc[g] = __builtin_amdgcn_mfma_f32_16x16x32_bf16(pf1, bv1, oacc[g], 0, 0, 0);
        }
    }

#pragma unroll
    for (int m = 1; m <= 8; m <<= 1) {
#pragma unroll
        for (int r = 0; r < 4; ++r) lsum[r] += __shfl_xor(lsum[r], m);
    }
    float gamma = gptr[0];
    float rl[4];
#pragma unroll
    for (int r = 0; r < 4; ++r) rl[r] = gamma / lsum[r];

    int ibase = i0 + wave * 16 + quad * 4;
#pragma unroll
    for (int g = 0; g < 4; ++g) {
        int c = g * 16 + l15;
        float4 xv = *(const float4*)(xb + (size_t)c * TT + ibase);
        float4 ov;
        ov.x = fmaf(oacc[g][0], rl[0], xv.x);
        ov.y = fmaf(oacc[g][1], rl[1], xv.y);
        ov.z = fmaf(oacc[g][2], rl[2], xv.z);
        ov.w = fmaf(oacc[g][3], rl[3], xv.w);
        *(float4*)(out + ((size_t)b * CHN + c) * TT + ibase) = ov;
    }
}

// ---------------------------------------------------------------------------
extern "C" void kernel_launch(void* const* d_in, const int* in_sizes, int n_in,
                              void* d_out, int out_size, void* d_ws, size_t ws_size,
                              hipStream_t stream) {
    const float* x  = (const float*)d_in[0];
    const float* w1 = (const float*)d_in[1];
    const float* w2 = (const float*)d_in[3];
    const float* gm = (const float*)d_in[5];
    float* out = (float*)d_out;

    const size_t XBYTES = (size_t)BB * CHN * TT * 2;   // 8 MB per bf16 copy
    if (ws_size >= 2 * XBYTES) {
        unsigned short* XtS = (unsigned short*)d_ws;
        unsigned short* XnS = (unsigned short*)((char*)d_ws + XBYTES);
        prep_kernel<<<BB * (TT / 64), 256, 0, stream>>>(x, XtS, XnS);
        attn_kernel<<<BB * (TT / 64), 256, 0, stream>>>(XtS, XnS, x, w1, w2, gm, out);
    } else {
        fused_attn_fallback<<<BB * (TT / 64), 256, 0, stream>>>(x, w1, w2, gm, out);
    }
}

// Round 9
// 419.106 us; speedup vs baseline: 1.0440x; 1.0440x over previous
//
#include <hip/hip_runtime.h>
#include <stdint.h>

// B=32, CH=64, T=2048. float32 in/out per the reference.
#define BB 32
#define CHN 64
#define TT 2048
#define LOG2E 1.4426950408889634f

typedef __attribute__((ext_vector_type(8))) short short8;
typedef __attribute__((ext_vector_type(4))) float f32x4;

#if defined(__has_builtin)
#if __has_builtin(__builtin_amdgcn_exp2f)
#define EXP2F __builtin_amdgcn_exp2f
#else
#define EXP2F exp2f
#endif
#else
#define EXP2F exp2f
#endif

// HW packed f32->bf16 (RNE), src0 -> low half, src1 -> high half.
__device__ __forceinline__ unsigned int pkbf(float a, float b) {
    unsigned int d;
    asm("v_cvt_pk_bf16_f32 %0, %1, %2" : "=v"(d) : "v"(a), "v"(b));
    return d;
}

__device__ __forceinline__ short8 cvt8(float4 q0, float4 q1) {
    union { unsigned int u[4]; short8 s; } v;
    v.u[0] = pkbf(q0.x, q0.y);
    v.u[1] = pkbf(q0.z, q0.w);
    v.u[2] = pkbf(q1.x, q1.y);
    v.u[3] = pkbf(q1.z, q1.w);
    return v.s;
}

// Transpose-staging swizzle for prep's LDS tile, element (t, c) -> short idx.
__device__ __forceinline__ int jt_idx(int t, int c) {
    int sw = ((t & 7) ^ ((t >> 3) & 7)) << 3;
    return t * 64 + (c ^ sw);
}

// Per-wave 16x64 P tile, (row=i-local, col=t-local) -> short idx (LDS).
__device__ __forceinline__ int pl_idx(int r, int c) {
    return r * 64 + (c ^ ((r & 7) << 3));
}

// ---------------------------------------------------------------------------
// Prep: one (b, 64-t chunk) per block.  Plain row-major bf16 chunk tiles:
//   XtS[b][ch]: [t-local 0..64)[c 0..64)   (Gram A/B fragments)
//   XnS[b][ch]: [c 0..64)[t-local 0..64)   (PV B fragments)
// b = blockIdx&31 keeps each batch's tiles on one XCD's L2 (round 6 win).
// ---------------------------------------------------------------------------
__global__ __launch_bounds__(256) void prep_kernel(
        const float* __restrict__ x,
        unsigned short* __restrict__ XtS,
        unsigned short* __restrict__ XnS) {
    __shared__ unsigned short Jt[64 * 64];
    int tid = threadIdx.x;
    int b  = blockIdx.x & 31;
    int ch = blockIdx.x >> 5;
    int t0 = ch * 64;
    const float* xb = x + (size_t)b * CHN * TT;
    unsigned short* xt_blk = XtS + (size_t)(b * 32 + ch) * 4096;
    unsigned short* xn_blk = XnS + (size_t)(b * 32 + ch) * 4096;

    int p = tid >> 3;              // c rows 2p, 2p+1
    int tsub = (tid & 7) * 8;      // 8 t per thread
    int r0 = 2 * p, r1 = 2 * p + 1;
    const float* s0 = xb + (size_t)r0 * TT + t0 + tsub;
    const float* s1 = s0 + TT;
    float4 qa = *(const float4*)s0, qb = *(const float4*)(s0 + 4);
    float4 qc = *(const float4*)s1, qd = *(const float4*)(s1 + 4);
    short8 v0 = cvt8(qa, qb);
    short8 v1 = cvt8(qc, qd);

    // XnS rows (plain)
    *(short8*)(xn_blk + (size_t)r0 * 64 + tsub) = v0;
    *(short8*)(xn_blk + (size_t)r1 * 64 + tsub) = v1;

    // transpose via LDS (packed c-pairs, swizzled against bank conflicts)
#pragma unroll
    for (int j = 0; j < 8; ++j) {
        int t = tsub + j;
        unsigned int pack = ((unsigned int)(unsigned short)v0[j]) |
                            (((unsigned int)(unsigned short)v1[j]) << 16);
        *(unsigned int*)&Jt[jt_idx(t, r0)] = pack;
    }
    __syncthreads();

    // XtS rows (plain): t = tid>>2, 16-c segment e = tid&3
    int t = tid >> 2, e = tid & 3;
    short8 w0 = *(const short8*)&Jt[jt_idx(t, e * 16)];
    short8 w1 = *(const short8*)&Jt[jt_idx(t, e * 16 + 8)];
    unsigned short* dst = xt_blk + (size_t)t * 64 + e * 16;
    *(short8*)dst = w0;
    *(short8*)(dst + 8) = w1;
}

// ---------------------------------------------------------------------------
// Attn: block = (b, 64 i-rows), b = blockIdx&31 (XCD affinity).
// Direct global b128 fragment loads from L2-resident XtS/XnS; no barriers,
// LDS only for the 1KB wave-private P tile.  Grid-limited 4 blocks/CU;
// __launch_bounds__(256,4) = 128-VGPR cap -> NO spills (round-8 lesson).
// ---------------------------------------------------------------------------
__global__ __launch_bounds__(256, 4) void attn_kernel(
        const unsigned short* __restrict__ XtS,
        const unsigned short* __restrict__ XnS,
        const float* __restrict__ x,
        const float* __restrict__ w1,
        const float* __restrict__ w2,
        const float* __restrict__ gptr,
        float* __restrict__ out) {
    __shared__ unsigned short Pl[4][1024];    // 8 KB total, wave-private

    int tid  = threadIdx.x;
    int b    = blockIdx.x & 31;
    int iblk = blockIdx.x >> 5;
    int wave = tid >> 6, lane = tid & 63;
    int quad = lane >> 4, l15 = lane & 15;
    int i0 = iblk * 64;

    const unsigned short* XtB = XtS + (size_t)b * 32 * 4096;
    const unsigned short* XnB = XnS + (size_t)b * 32 * 4096;
    const float* xb = x + (size_t)b * CHN * TT;

    float s11 = 0.f;
#pragma unroll
    for (int h = 0; h < 8; ++h) s11 += w1[h] * w2[h];

    // A fragments: rows i0 + wave*16 + l15, direct from XtS
    const unsigned short* arow = XtB + (size_t)iblk * 4096 +
                                 (size_t)(wave * 16 + l15) * 64 + quad * 8;
    short8 a0 = *(const short8*)arow;
    short8 a1 = *(const short8*)(arow + 32);

    // ---- Phase 1: raw-Gram row min/max ----
    float vmin[4], vmax[4];
#pragma unroll
    for (int r = 0; r < 4; ++r) { vmin[r] = 3.4e38f; vmax[r] = -3.4e38f; }

    const unsigned short* fb = XtB + (size_t)l15 * 64 + quad * 8;
#pragma unroll 2
    for (int m = 0; m < 32; ++m) {
        const unsigned short* tp = fb + (size_t)m * 4096;
#pragma unroll
        for (int sub = 0; sub < 4; ++sub) {
            const unsigned short* brow = tp + (size_t)sub * (16 * 64);
            short8 b0 = *(const short8*)brow;
            short8 b1 = *(const short8*)(brow + 32);
            f32x4 acc = {0.f, 0.f, 0.f, 0.f};
            acc = __builtin_amdgcn_mfma_f32_16x16x32_bf16(a0, b0, acc, 0, 0, 0);
            acc = __builtin_amdgcn_mfma_f32_16x16x32_bf16(a1, b1, acc, 0, 0, 0);
#pragma unroll
            for (int r = 0; r < 4; ++r) {
                vmin[r] = fminf(vmin[r], acc[r]);
                vmax[r] = fmaxf(vmax[r], acc[r]);
            }
        }
    }
#pragma unroll
    for (int m = 1; m <= 8; m <<= 1) {
#pragma unroll
        for (int r = 0; r < 4; ++r) {
            vmin[r] = fminf(vmin[r], __shfl_xor(vmin[r], m));
            vmax[r] = fmaxf(vmax[r], __shfl_xor(vmax[r], m));
        }
    }
    float rdl2[4], mlog[4];
#pragma unroll
    for (int r = 0; r < 4; ++r) {
        float e0 = s11 * vmin[r], e1 = s11 * vmax[r];
        float mn = fminf(e0, e1), mx = fmaxf(e0, e1);
        float rd = LOG2E / (mx - mn + 1e-8f);
        rdl2[r] = s11 * rd;      // applied to raw Gram acc
        mlog[r] = mn * rd;
    }

    // ---- Phase 2: P = exp2(acc*rdl2 - mlog) -> (LDS turn) -> PV ----
    f32x4 oacc[4];
#pragma unroll
    for (int g = 0; g < 4; ++g) oacc[g] = (f32x4){0.f, 0.f, 0.f, 0.f};
    float lsum[4] = {0.f, 0.f, 0.f, 0.f};
    unsigned short* Pw = &Pl[wave][0];

    const unsigned short* nb = XnB + (size_t)l15 * 64 + quad * 8;
    for (int m = 0; m < 32; ++m) {
        const unsigned short* tp = fb + (size_t)m * 4096;
        const unsigned short* xn = nb + (size_t)m * 4096;
#pragma unroll
        for (int sub = 0; sub < 4; ++sub) {
            const unsigned short* brow = tp + (size_t)sub * (16 * 64);
            short8 b0 = *(const short8*)brow;
            short8 b1 = *(const short8*)(brow + 32);
            f32x4 acc = {0.f, 0.f, 0.f, 0.f};
            acc = __builtin_amdgcn_mfma_f32_16x16x32_bf16(a0, b0, acc, 0, 0, 0);
            acc = __builtin_amdgcn_mfma_f32_16x16x32_bf16(a1, b1, acc, 0, 0, 0);
            float pv0 = EXP2F(fmaf(acc[0], rdl2[0], -mlog[0]));
            float pv1 = EXP2F(fmaf(acc[1], rdl2[1], -mlog[1]));
            float pv2 = EXP2F(fmaf(acc[2], rdl2[2], -mlog[2]));
            float pv3 = EXP2F(fmaf(acc[3], rdl2[3], -mlog[3]));
            lsum[0] += pv0; lsum[1] += pv1; lsum[2] += pv2; lsum[3] += pv3;
            unsigned int k01 = pkbf(pv0, pv1);
            unsigned int k23 = pkbf(pv2, pv3);
            Pw[pl_idx(quad * 4 + 0, sub * 16 + l15)] = (unsigned short)k01;
            Pw[pl_idx(quad * 4 + 1, sub * 16 + l15)] = (unsigned short)(k01 >> 16);
            Pw[pl_idx(quad * 4 + 2, sub * 16 + l15)] = (unsigned short)k23;
            Pw[pl_idx(quad * 4 + 3, sub * 16 + l15)] = (unsigned short)(k23 >> 16);
        }
        // own-wave DS ordering (P slice is wave-private; DS retires in-order)
        asm volatile("s_waitcnt lgkmcnt(0)" ::: "memory");
        short8 pf0 = *(const short8*)&Pw[pl_idx(l15, quad * 8)];
        short8 pf1 = *(const short8*)&Pw[pl_idx(l15, 32 + quad * 8)];
#pragma unroll
        for (int g = 0; g < 4; ++g) {
            const unsigned short* vr = xn + (size_t)g * (16 * 64);
            short8 bv0 = *(const short8*)vr;
            short8 bv1 = *(const short8*)(vr + 32);
            oacc[g] = __builtin_amdgcn_mfma_f32_16x16x32_bf16(pf0, bv0, oacc[g], 0, 0, 0);
            oacc[g] = __builtin_amdgcn_mfma_f32_16x16x32_bf16(pf1, bv1, oacc[g], 0, 0, 0);
        }
    }

    // ---- Epilogue ----
#pragma unroll
    for (int m = 1; m <= 8; m <<= 1) {
#pragma unroll
        for (int r = 0; r < 4; ++r) lsum[r] += __shfl_xor(lsum[r], m);
    }
    float gamma = gptr[0];
    float rl[4];
#pragma unroll
    for (int r = 0; r < 4; ++r) rl[r] = gamma / lsum[r];

    int ibase = i0 + wave * 16 + quad * 4;
#pragma unroll
    for (int g = 0; g < 4; ++g) {
        int c = g * 16 + l15;
        float4 xv = *(const float4*)(xb + (size_t)c * TT + ibase);
        float4 ov;
        ov.x = fmaf(oacc[g][0], rl[0], xv.x);
        ov.y = fmaf(oacc[g][1], rl[1], xv.y);
        ov.z = fmaf(oacc[g][2], rl[2], xv.z);
        ov.w = fmaf(oacc[g][3], rl[3], xv.w);
        *(float4*)(out + ((size_t)b * CHN + c) * TT + ibase) = ov;
    }
}

// ---------------------------------------------------------------------------
// Fallback (round-3 structure, zero workspace) — only if ws < 16 MB.
// ---------------------------------------------------------------------------
__device__ __forceinline__ void stage_tile_fb(const float* __restrict__ xb,
                                              int tbase, unsigned short* Jt, int tid) {
    int p = tid >> 3;
    int tsub = (tid & 7) * 8;
    const float* s0 = xb + (size_t)(2 * p) * TT + tbase + tsub;
    const float* s1 = s0 + TT;
    float4 a0 = *(const float4*)s0;
    float4 a1 = *(const float4*)(s0 + 4);
    float4 b0 = *(const float4*)s1;
    float4 b1 = *(const float4*)(s1 + 4);
    short8 v0 = cvt8(a0, a1);
    short8 v1 = cvt8(b0, b1);
#pragma unroll
    for (int j = 0; j < 8; ++j) {
        int t = tsub + j;
        unsigned int pack = ((unsigned int)(unsigned short)v0[j]) |
                            (((unsigned int)(unsigned short)v1[j]) << 16);
        *(unsigned int*)&Jt[jt_idx(t, 2 * p)] = pack;
    }
}

__global__ __launch_bounds__(256) void fused_attn_fallback(
        const float* __restrict__ x,
        const float* __restrict__ w1,
        const float* __restrict__ w2,
        const float* __restrict__ gptr,
        float* __restrict__ out) {
    __shared__ unsigned short Jt[64 * 64];
    __shared__ unsigned short Pl[4][16 * 64];

    int tid  = threadIdx.x;
    int b    = blockIdx.x >> 5;
    int iblk = blockIdx.x & 31;
    int wave = tid >> 6;
    int lane = tid & 63;
    int quad = lane >> 4, l15 = lane & 15;
    int i0 = iblk * 64;
    const float* xb = x + (size_t)b * CHN * TT;

    float s11 = 0.f;
#pragma unroll
    for (int h = 0; h < 8; ++h) s11 += w1[h] * w2[h];

    stage_tile_fb(xb, i0, Jt, tid);
    __syncthreads();
    short8 a0 = *(const short8*)&Jt[jt_idx(wave * 16 + l15, quad * 8)];
    short8 a1 = *(const short8*)&Jt[jt_idx(wave * 16 + l15, 32 + quad * 8)];

    float vmin[4], vmax[4];
#pragma unroll
    for (int r = 0; r < 4; ++r) { vmin[r] = 3.4e38f; vmax[r] = -3.4e38f; }

    for (int t0 = 0; t0 < TT; t0 += 64) {
        __syncthreads();
        stage_tile_fb(xb, t0, Jt, tid);
        __syncthreads();
#pragma unroll
        for (int sub = 0; sub < 4; ++sub) {
            short8 b0 = *(const short8*)&Jt[jt_idx(sub * 16 + l15, quad * 8)];
            short8 b1 = *(const short8*)&Jt[jt_idx(sub * 16 + l15, 32 + quad * 8)];
            f32x4 acc = {0.f, 0.f, 0.f, 0.f};
            acc = __builtin_amdgcn_mfma_f32_16x16x32_bf16(a0, b0, acc, 0, 0, 0);
            acc = __builtin_amdgcn_mfma_f32_16x16x32_bf16(a1, b1, acc, 0, 0, 0);
#pragma unroll
            for (int r = 0; r < 4; ++r) {
                vmin[r] = fminf(vmin[r], acc[r]);
                vmax[r] = fmaxf(vmax[r], acc[r]);
            }
        }
    }
#pragma unroll
    for (int m = 1; m <= 8; m <<= 1) {
#pragma unroll
        for (int r = 0; r < 4; ++r) {
            vmin[r] = fminf(vmin[r], __shfl_xor(vmin[r], m));
            vmax[r] = fmaxf(vmax[r], __shfl_xor(vmax[r], m));
        }
    }
    float rdl2[4], mlog[4];
#pragma unroll
    for (int r = 0; r < 4; ++r) {
        float e0 = s11 * vmin[r], e1 = s11 * vmax[r];
        float mn = fminf(e0, e1), mx = fmaxf(e0, e1);
        float rd = LOG2E / (mx - mn + 1e-8f);
        rdl2[r] = s11 * rd;
        mlog[r] = mn * rd;
    }

    f32x4 oacc[4];
#pragma unroll
    for (int g = 0; g < 4; ++g) oacc[g] = (f32x4){0.f, 0.f, 0.f, 0.f};
    float lsum[4] = {0.f, 0.f, 0.f, 0.f};
    unsigned short* Pw = &Pl[wave][0];

    for (int t0 = 0; t0 < TT; t0 += 64) {
        __syncthreads();
        stage_tile_fb(xb, t0, Jt, tid);
        __syncthreads();
#pragma unroll
        for (int sub = 0; sub < 4; ++sub) {
            short8 b0 = *(const short8*)&Jt[jt_idx(sub * 16 + l15, quad * 8)];
            short8 b1 = *(const short8*)&Jt[jt_idx(sub * 16 + l15, 32 + quad * 8)];
            f32x4 acc = {0.f, 0.f, 0.f, 0.f};
            acc = __builtin_amdgcn_mfma_f32_16x16x32_bf16(a0, b0, acc, 0, 0, 0);
            acc = __builtin_amdgcn_mfma_f32_16x16x32_bf16(a1, b1, acc, 0, 0, 0);
            float pv0 = EXP2F(fmaf(acc[0], rdl2[0], -mlog[0]));
            float pv1 = EXP2F(fmaf(acc[1], rdl2[1], -mlog[1]));
            float pv2 = EXP2F(fmaf(acc[2], rdl2[2], -mlog[2]));
            float pv3 = EXP2F(fmaf(acc[3], rdl2[3], -mlog[3]));
            lsum[0] += pv0; lsum[1] += pv1; lsum[2] += pv2; lsum[3] += pv3;
            unsigned int k01 = pkbf(pv0, pv1);
            unsigned int k23 = pkbf(pv2, pv3);
            Pw[pl_idx(quad * 4 + 0, sub * 16 + l15)] = (unsigned short)k01;
            Pw[pl_idx(quad * 4 + 1, sub * 16 + l15)] = (unsigned short)(k01 >> 16);
            Pw[pl_idx(quad * 4 + 2, sub * 16 + l15)] = (unsigned short)k23;
            Pw[pl_idx(quad * 4 + 3, sub * 16 + l15)] = (unsigned short)(k23 >> 16);
        }
        asm volatile("s_waitcnt lgkmcnt(0)" ::: "memory");
        short8 pf0 = *(const short8*)&Pw[pl_idx(l15, quad * 8)];
        short8 pf1 = *(const short8*)&Pw[pl_idx(l15, 32 + quad * 8)];
#pragma unroll
        for (int g = 0; g < 4; ++g) {
            const float* vr = xb + (size_t)(g * 16 + l15) * TT + t0;
            float4 q0 = *(const float4*)(vr + quad * 8);
            float4 q1 = *(const float4*)(vr + quad * 8 + 4);
            float4 q2 = *(const float4*)(vr + 32 + quad * 8);
            float4 q3 = *(const float4*)(vr + 32 + quad * 8 + 4);
            short8 bv0 = cvt8(q0, q1);
            short8 bv1 = cvt8(q2, q3);
            oacc[g] = __builtin_amdgcn_mfma_f32_16x16x32_bf16(pf0, bv0, oacc[g], 0, 0, 0);
            oacc[g] = __builtin_amdgcn_mfma_f32_16x16x32_bf16(pf1, bv1, oacc[g], 0, 0, 0);
        }
    }

#pragma unroll
    for (int m = 1; m <= 8; m <<= 1) {
#pragma unroll
        for (int r = 0; r < 4; ++r) lsum[r] += __shfl_xor(lsum[r], m);
    }
    float gamma = gptr[0];
    float rl[4];
#pragma unroll
    for (int r = 0; r < 4; ++r) rl[r] = gamma / lsum[r];

    int ibase = i0 + wave * 16 + quad * 4;
#pragma unroll
    for (int g = 0; g < 4; ++g) {
        int c = g * 16 + l15;
        float4 xv = *(const float4*)(xb + (size_t)c * TT + ibase);
        float4 ov;
        ov.x = fmaf(oacc[g][0], rl[0], xv.x);
        ov.y = fmaf(oacc[g][1], rl[1], xv.y);
        ov.z = fmaf(oacc[g][2], rl[2], xv.z);
        ov.w = fmaf(oacc[g][3], rl[3], xv.w);
        *(float4*)(out + ((size_t)b * CHN + c) * TT + ibase) = ov;
    }
}

// ---------------------------------------------------------------------------
extern "C" void kernel_launch(void* const* d_in, const int* in_sizes, int n_in,
                              void* d_out, int out_size, void* d_ws, size_t ws_size,
                              hipStream_t stream) {
    const float* x  = (const float*)d_in[0];
    const float* w1 = (const float*)d_in[1];
    const float* w2 = (const float*)d_in[3];
    const float* gm = (const float*)d_in[5];
    float* out = (float*)d_out;

    const size_t XBYTES = (size_t)BB * CHN * TT * 2;   // 8 MB per bf16 copy
    if (ws_size >= 2 * XBYTES) {
        unsigned short* XtS = (unsigned short*)d_ws;
        unsigned short* XnS = (unsigned short*)((char*)d_ws + XBYTES);
        prep_kernel<<<BB * (TT / 64), 256, 0, stream>>>(x, XtS, XnS);
        attn_kernel<<<BB * (TT / 64), 256, 0, stream>>>(XtS, XnS, x, w1, w2, gm, out);
    } else {
        fused_attn_fallback<<<BB * (TT / 64), 256, 0, stream>>>(x, w1, w2, gm, out);
    }
}

// Round 11
// 194.779 us; speedup vs baseline: 2.2463x; 2.1517x over previous
//
#include <hip/hip_runtime.h>
#include <stdint.h>

// B=32, CH=64, T=2048. float32 in/out per the reference.
#define BB 32
#define CHN 64
#define TT 2048
#define LOG2E 1.4426950408889634f

typedef __attribute__((ext_vector_type(8))) short short8;
typedef __attribute__((ext_vector_type(4))) float f32x4;

#if defined(__has_builtin)
#if __has_builtin(__builtin_amdgcn_exp2f)
#define EXP2F __builtin_amdgcn_exp2f
#else
#define EXP2F exp2f
#endif
#else
#define EXP2F exp2f
#endif

#if defined(__has_builtin)
#if __has_builtin(__builtin_amdgcn_global_load_lds)
#define HAS_GLL 1
#endif
#endif

#ifdef HAS_GLL
typedef const __attribute__((address_space(1))) unsigned int* gas_t;
typedef __attribute__((address_space(3))) unsigned int* las_t;
__device__ __forceinline__ void async16(const void* g, void* l) {
    __builtin_amdgcn_global_load_lds((gas_t)g, (las_t)l, 16, 0, 0);
}
#endif

#define WAITALL asm volatile("s_waitcnt vmcnt(0) lgkmcnt(0)" ::: "memory")

// HW packed f32->bf16 (RNE), src0 -> low half, src1 -> high half.
__device__ __forceinline__ unsigned int pkbf(float a, float b) {
    unsigned int d;
    asm("v_cvt_pk_bf16_f32 %0, %1, %2" : "=v"(d) : "v"(a), "v"(b));
    return d;
}

__device__ __forceinline__ short8 cvt8(float4 q0, float4 q1) {
    union { unsigned int u[4]; short8 s; } v;
    v.u[0] = pkbf(q0.x, q0.y);
    v.u[1] = pkbf(q0.z, q0.w);
    v.u[2] = pkbf(q1.x, q1.y);
    v.u[3] = pkbf(q1.z, q1.w);
    return v.s;
}

// Chunk tile addressing: 64 rows x 8 segs of 8 shorts (16B), XOR-swizzled.
// Layout is identical in global (pre-swizzled by prep) and in LDS (stage8k
// is a pure linear copy), so the same index works on either copy.
#define XT_IDX(row, cseg) (((row) << 6) + ((((cseg) ^ ((row) & 7))) << 3))

// Transpose-staging swizzle for prep's LDS tile, element (t, c) -> short idx.
__device__ __forceinline__ int jt_idx(int t, int c) {
    int sw = ((t & 7) ^ ((t >> 3) & 7)) << 3;
    return t * 64 + (c ^ sw);
}

// Per-wave 16x64 P tile, (row=i-local, col=t-local) -> short idx.
__device__ __forceinline__ int pl_idx(int r, int c) {
    return r * 64 + (c ^ ((r & 7) << 3));
}

// ---------------------------------------------------------------------------
// Prep (round-7 verbatim): one (b, 64-t chunk) per block.  Emits two
// pre-swizzled 8KB chunk tiles:
//   XtS[b][ch]: seg s=row*8+seg' holds Xt[t0+row][c=(seg'^(row&7))*8 ..+8]
//   XnS[b][ch]: seg s=row*8+seg' holds Xn[c=row][t0+(seg'^(row&7))*8 ..+8]
// b = blockIdx&31 keeps each batch's tiles on one XCD's L2.
// ---------------------------------------------------------------------------
__global__ __launch_bounds__(256) void prep_kernel(
        const float* __restrict__ x,
        unsigned short* __restrict__ XtS,
        unsigned short* __restrict__ XnS) {
    __shared__ unsigned short Jt[64 * 64];
    int tid = threadIdx.x;
    int b  = blockIdx.x & 31;
    int ch = blockIdx.x >> 5;
    int t0 = ch * 64;
    const float* xb = x + (size_t)b * CHN * TT;
    unsigned short* xt_blk = XtS + (size_t)(b * 32 + ch) * 4096;
    unsigned short* xn_blk = XnS + (size_t)(b * 32 + ch) * 4096;

    int p = tid >> 3;              // c rows 2p, 2p+1
    int tsub = (tid & 7) * 8;      // 8 t per thread
    int r0 = 2 * p, r1 = 2 * p + 1;
    const float* s0 = xb + (size_t)r0 * TT + t0 + tsub;
    const float* s1 = s0 + TT;
    float4 qa = *(const float4*)s0, qb = *(const float4*)(s0 + 4);
    float4 qc = *(const float4*)s1, qd = *(const float4*)(s1 + 4);
    short8 v0 = cvt8(qa, qb);
    short8 v1 = cvt8(qc, qd);

    // XnS segments (row = c, seg covers t tsub..+8)
    int seg = tsub >> 3;
    *(short8*)(xn_blk + ((size_t)(r0 * 8 + (seg ^ (r0 & 7)))) * 8) = v0;
    *(short8*)(xn_blk + ((size_t)(r1 * 8 + (seg ^ (r1 & 7)))) * 8) = v1;

    // transpose via LDS (packed c-pairs)
#pragma unroll
    for (int j = 0; j < 8; ++j) {
        int t = tsub + j;
        unsigned int pack = ((unsigned int)(unsigned short)v0[j]) |
                            (((unsigned int)(unsigned short)v1[j]) << 16);
        *(unsigned int*)&Jt[jt_idx(t, r0)] = pack;
    }
    __syncthreads();

    // XtS segments (row = t, seg covers 8 c)
    int t = tid >> 2, e = tid & 3;
#pragma unroll
    for (int k = 0; k < 2; ++k) {
        int cs = 2 * e + k;
        short8 vv = *(const short8*)&Jt[jt_idx(t, cs * 8)];
        *(short8*)(xt_blk + ((size_t)(t * 8 + (cs ^ (t & 7)))) * 8) = vv;
    }
}

// Stage one 8KB chunk tile: pure linear copy, wave w covers segs [w*128,+128).
__device__ __forceinline__ void stage8k(const unsigned short* __restrict__ g,
                                        unsigned short* l, int wave, int lane) {
#ifdef HAS_GLL
    const unsigned short* gs = g + (size_t)(wave * 128 + lane) * 8;
    unsigned short* ls = l + wave * 1024;
    async16(gs, ls);
    async16(gs + 512, ls + 512);
#else
    const short8* gs = (const short8*)g + (wave * 128 + lane);
    short8* ls = (short8*)l + (wave * 128 + lane);
    ls[0] = gs[0];
    ls[64] = gs[64];
#endif
}

// ---------------------------------------------------------------------------
// Attn (round-7 base): block = (b, 64 i-rows), b = blockIdx&31 (XCD affinity).
// Double-buffered global_load_lds staging for the Gram Xt stream.
// DELTA vs round 7: PV B-frags (xv) read DIRECTLY from global XnS chunks
// (same XT_IDX offsets; L2/L1-resident), issued before the Gram sub-loop.
// Removes the Xn2 LDS buffers, their DMA, and 384 LDS-read cyc/block-iter.
// ---------------------------------------------------------------------------
__global__ __launch_bounds__(256) void attn_kernel(
        const unsigned short* __restrict__ XtS,
        const unsigned short* __restrict__ XnS,
        const float* __restrict__ x,
        const float* __restrict__ w1,
        const float* __restrict__ w2,
        const float* __restrict__ gptr,
        float* __restrict__ out) {
    __shared__ unsigned short Xt2[2][4096];   // 16 KB
    __shared__ unsigned short Pl[4][1024];    // 8 KB, wave-private

    int tid  = threadIdx.x;
    int b    = blockIdx.x & 31;
    int iblk = blockIdx.x >> 5;
    int wave = tid >> 6, lane = tid & 63;
    int quad = lane >> 4, l15 = lane & 15;
    int i0 = iblk * 64;

    const unsigned short* XtB = XtS + (size_t)b * 32 * 4096;
    const unsigned short* XnB = XnS + (size_t)b * 32 * 4096;
    const float* xb = x + (size_t)b * CHN * TT;

    float s11 = 0.f;
#pragma unroll
    for (int h = 0; h < 8; ++h) s11 += w1[h] * w2[h];

    // ---- Phase 1 prologue: stage own i-chunk ----
    stage8k(XtB + (size_t)iblk * 4096, &Xt2[0][0], wave, lane);
    WAITALL;
    __syncthreads();

    int arow = wave * 16 + l15;
    short8 a0 = *(const short8*)&Xt2[0][XT_IDX(arow, quad)];
    short8 a1 = *(const short8*)&Xt2[0][XT_IDX(arow, quad + 4)];

    float vmin[4], vmax[4];
#pragma unroll
    for (int r = 0; r < 4; ++r) { vmin[r] = 3.4e38f; vmax[r] = -3.4e38f; }

    for (int m = 0; m < 32; ++m) {
        int buf = m & 1;
        if (m < 31)
            stage8k(XtB + (size_t)((iblk + m + 1) & 31) * 4096,
                    &Xt2[buf ^ 1][0], wave, lane);
        const unsigned short* tp = &Xt2[buf][0];
#pragma unroll
        for (int sub = 0; sub < 4; ++sub) {
            int row = sub * 16 + l15;
            short8 b0 = *(const short8*)&tp[XT_IDX(row, quad)];
            short8 b1 = *(const short8*)&tp[XT_IDX(row, quad + 4)];
            f32x4 acc = {0.f, 0.f, 0.f, 0.f};
            acc = __builtin_amdgcn_mfma_f32_16x16x32_bf16(a0, b0, acc, 0, 0, 0);
            acc = __builtin_amdgcn_mfma_f32_16x16x32_bf16(a1, b1, acc, 0, 0, 0);
#pragma unroll
            for (int r = 0; r < 4; ++r) {
                vmin[r] = fminf(vmin[r], acc[r]);
                vmax[r] = fmaxf(vmax[r], acc[r]);
            }
        }
        WAITALL;
        __syncthreads();
    }

    // ---- Phase transition: stage first phase-2 Xt tile while reducing ----
    stage8k(XtB, &Xt2[0][0], wave, lane);

#pragma unroll
    for (int m = 1; m <= 8; m <<= 1) {
#pragma unroll
        for (int r = 0; r < 4; ++r) {
            vmin[r] = fminf(vmin[r], __shfl_xor(vmin[r], m));
            vmax[r] = fmaxf(vmax[r], __shfl_xor(vmax[r], m));
        }
    }
    float rdl2[4], mlog[4];
#pragma unroll
    for (int r = 0; r < 4; ++r) {
        float e0 = s11 * vmin[r], e1 = s11 * vmax[r];
        float mn = fminf(e0, e1), mx = fmaxf(e0, e1);
        float rd = LOG2E / (mx - mn + 1e-8f);
        rdl2[r] = s11 * rd;      // applied to raw Gram acc
        mlog[r] = mn * rd;
    }

    f32x4 oacc[4];
#pragma unroll
    for (int g = 0; g < 4; ++g) oacc[g] = (f32x4){0.f, 0.f, 0.f, 0.f};
    float lsum[4] = {0.f, 0.f, 0.f, 0.f};
    unsigned short* Pw = &Pl[wave][0];

    WAITALL;
    __syncthreads();

    // ---- Phase 2 ----
    for (int m = 0; m < 32; ++m) {
        int buf = m & 1;
        if (m < 31)
            stage8k(XtB + (size_t)(m + 1) * 4096, &Xt2[buf ^ 1][0], wave, lane);

        // PV B-frags: direct global reads from the chunked XnS (early issue;
        // Gram + exp2 section below covers their latency).
        const unsigned short* xnc = XnB + (size_t)m * 4096;
        short8 xv[4][2];
#pragma unroll
        for (int g = 0; g < 4; ++g) {
            int row = g * 16 + l15;
            xv[g][0] = *(const short8*)&xnc[XT_IDX(row, quad)];
            xv[g][1] = *(const short8*)&xnc[XT_IDX(row, quad + 4)];
        }

        const unsigned short* tp = &Xt2[buf][0];
#pragma unroll
        for (int sub = 0; sub < 4; ++sub) {
            int row = sub * 16 + l15;
            short8 b0 = *(const short8*)&tp[XT_IDX(row, quad)];
            short8 b1 = *(const short8*)&tp[XT_IDX(row, quad + 4)];
            f32x4 acc = {0.f, 0.f, 0.f, 0.f};
            acc = __builtin_amdgcn_mfma_f32_16x16x32_bf16(a0, b0, acc, 0, 0, 0);
            acc = __builtin_amdgcn_mfma_f32_16x16x32_bf16(a1, b1, acc, 0, 0, 0);
            float pv0 = EXP2F(fmaf(acc[0], rdl2[0], -mlog[0]));
            float pv1 = EXP2F(fmaf(acc[1], rdl2[1], -mlog[1]));
            float pv2 = EXP2F(fmaf(acc[2], rdl2[2], -mlog[2]));
            float pv3 = EXP2F(fmaf(acc[3], rdl2[3], -mlog[3]));
            lsum[0] += pv0; lsum[1] += pv1; lsum[2] += pv2; lsum[3] += pv3;
            unsigned int k01 = pkbf(pv0, pv1);
            unsigned int k23 = pkbf(pv2, pv3);
            Pw[pl_idx(quad * 4 + 0, sub * 16 + l15)] = (unsigned short)k01;
            Pw[pl_idx(quad * 4 + 1, sub * 16 + l15)] = (unsigned short)(k01 >> 16);
            Pw[pl_idx(quad * 4 + 2, sub * 16 + l15)] = (unsigned short)k23;
            Pw[pl_idx(quad * 4 + 3, sub * 16 + l15)] = (unsigned short)(k23 >> 16);
        }
        // own-wave DS ordering: P writes retire before P reads issue results
        asm volatile("s_waitcnt lgkmcnt(0)" ::: "memory");
        short8 pf0 = *(const short8*)&Pw[pl_idx(l15, quad * 8)];
        short8 pf1 = *(const short8*)&Pw[pl_idx(l15, 32 + quad * 8)];
#pragma unroll
        for (int g = 0; g < 4; ++g) {
            oacc[g] = __builtin_amdgcn_mfma_f32_16x16x32_bf16(pf0, xv[g][0], oacc[g], 0, 0, 0);
            oacc[g] = __builtin_amdgcn_mfma_f32_16x16x32_bf16(pf1, xv[g][1], oacc[g], 0, 0, 0);
        }
        WAITALL;
        __syncthreads();
    }

    // ---- Epilogue ----
#pragma unroll
    for (int m = 1; m <= 8; m <<= 1) {
#pragma unroll
        for (int r = 0; r < 4; ++r) lsum[r] += __shfl_xor(lsum[r], m);
    }
    float gamma = gptr[0];
    float rl[4];
#pragma unroll
    for (int r = 0; r < 4; ++r) rl[r] = gamma / lsum[r];

    int ibase = i0 + wave * 16 + quad * 4;
#pragma unroll
    for (int g = 0; g < 4; ++g) {
        int c = g * 16 + l15;
        float4 xvv = *(const float4*)(xb + (size_t)c * TT + ibase);
        float4 ov;
        ov.x = fmaf(oacc[g][0], rl[0], xvv.x);
        ov.y = fmaf(oacc[g][1], rl[1], xvv.y);
        ov.z = fmaf(oacc[g][2], rl[2], xvv.z);
        ov.w = fmaf(oacc[g][3], rl[3], xvv.w);
        *(float4*)(out + ((size_t)b * CHN + c) * TT + ibase) = ov;
    }
}

// ---------------------------------------------------------------------------
// Fallback (round-3 structure, zero workspace) — only if ws < 16 MB.
// ---------------------------------------------------------------------------
__device__ __forceinline__ void stage_tile_fb(const float* __restrict__ xb,
                                              int tbase, unsigned short* Jt, int tid) {
    int p = tid >> 3;
    int tsub = (tid & 7) * 8;
    const float* s0 = xb + (size_t)(2 * p) * TT + tbase + tsub;
    const float* s1 = s0 + TT;
    float4 a0 = *(const float4*)s0;
    float4 a1 = *(const float4*)(s0 + 4);
    float4 b0 = *(const float4*)s1;
    float4 b1 = *(const float4*)(s1 + 4);
    short8 v0 = cvt8(a0, a1);
    short8 v1 = cvt8(b0, b1);
#pragma unroll
    for (int j = 0; j < 8; ++j) {
        int t = tsub + j;
        unsigned int pack = ((unsigned int)(unsigned short)v0[j]) |
                            (((unsigned int)(unsigned short)v1[j]) << 16);
        *(unsigned int*)&Jt[jt_idx(t, 2 * p)] = pack;
    }
}

__global__ __launch_bounds__(256) void fused_attn_fallback(
        const float* __restrict__ x,
        const float* __restrict__ w1,
        const float* __restrict__ w2,
        const float* __restrict__ gptr,
        float* __restrict__ out) {
    __shared__ unsigned short Jt[64 * 64];
    __shared__ unsigned short Pl[4][16 * 64];

    int tid  = threadIdx.x;
    int b    = blockIdx.x >> 5;
    int iblk = blockIdx.x & 31;
    int wave = tid >> 6;
    int lane = tid & 63;
    int quad = lane >> 4, l15 = lane & 15;
    int i0 = iblk * 64;
    const float* xb = x + (size_t)b * CHN * TT;

    float s11 = 0.f;
#pragma unroll
    for (int h = 0; h < 8; ++h) s11 += w1[h] * w2[h];

    stage_tile_fb(xb, i0, Jt, tid);
    __syncthreads();
    short8 a0 = *(const short8*)&Jt[jt_idx(wave * 16 + l15, quad * 8)];
    short8 a1 = *(const short8*)&Jt[jt_idx(wave * 16 + l15, 32 + quad * 8)];

    float vmin[4], vmax[4];
#pragma unroll
    for (int r = 0; r < 4; ++r) { vmin[r] = 3.4e38f; vmax[r] = -3.4e38f; }

    for (int t0 = 0; t0 < TT; t0 += 64) {
        __syncthreads();
        stage_tile_fb(xb, t0, Jt, tid);
        __syncthreads();
#pragma unroll
        for (int sub = 0; sub < 4; ++sub) {
            short8 b0 = *(const short8*)&Jt[jt_idx(sub * 16 + l15, quad * 8)];
            short8 b1 = *(const short8*)&Jt[jt_idx(sub * 16 + l15, 32 + quad * 8)];
            f32x4 acc = {0.f, 0.f, 0.f, 0.f};
            acc = __builtin_amdgcn_mfma_f32_16x16x32_bf16(a0, b0, acc, 0, 0, 0);
            acc = __builtin_amdgcn_mfma_f32_16x16x32_bf16(a1, b1, acc, 0, 0, 0);
#pragma unroll
            for (int r = 0; r < 4; ++r) {
                vmin[r] = fminf(vmin[r], acc[r]);
                vmax[r] = fmaxf(vmax[r], acc[r]);
            }
        }
    }
#pragma unroll
    for (int m = 1; m <= 8; m <<= 1) {
#pragma unroll
        for (int r = 0; r < 4; ++r) {
            vmin[r] = fminf(vmin[r], __shfl_xor(vmin[r], m));
            vmax[r] = fmaxf(vmax[r], __shfl_xor(vmax[r], m));
        }
    }
    float rdl2[4], mlog[4];
#pragma unroll
    for (int r = 0; r < 4; ++r) {
        float e0 = s11 * vmin[r], e1 = s11 * vmax[r];
        float mn = fminf(e0, e1), mx = fmaxf(e0, e1);
        float rd = LOG2E / (mx - mn + 1e-8f);
        rdl2[r] = s11 * rd;
        mlog[r] = mn * rd;
    }

    f32x4 oacc[4];
#pragma unroll
    for (int g = 0; g < 4; ++g) oacc[g] = (f32x4){0.f, 0.f, 0.f, 0.f};
    float lsum[4] = {0.f, 0.f, 0.f, 0.f};
    unsigned short* Pw = &Pl[wave][0];

    for (int t0 = 0; t0 < TT; t0 += 64) {
        __syncthreads();
        stage_tile_fb(xb, t0, Jt, tid);
        __syncthreads();
#pragma unroll
        for (int sub = 0; sub < 4; ++sub) {
            short8 b0 = *(const short8*)&Jt[jt_idx(sub * 16 + l15, quad * 8)];
            short8 b1 = *(const short8*)&Jt[jt_idx(sub * 16 + l15, 32 + quad * 8)];
            f32x4 acc = {0.f, 0.f, 0.f, 0.f};
            acc = __builtin_amdgcn_mfma_f32_16x16x32_bf16(a0, b0, acc, 0, 0, 0);
            acc = __builtin_amdgcn_mfma_f32_16x16x32_bf16(a1, b1, acc, 0, 0, 0);
            float pv0 = EXP2F(fmaf(acc[0], rdl2[0], -mlog[0]));
            float pv1 = EXP2F(fmaf(acc[1], rdl2[1], -mlog[1]));
            float pv2 = EXP2F(fmaf(acc[2], rdl2[2], -mlog[2]));
            float pv3 = EXP2F(fmaf(acc[3], rdl2[3], -mlog[3]));
            lsum[0] += pv0; lsum[1] += pv1; lsum[2] += pv2; lsum[3] += pv3;
            unsigned int k01 = pkbf(pv0, pv1);
            unsigned int k23 = pkbf(pv2, pv3);
            Pw[pl_idx(quad * 4 + 0, sub * 16 + l15)] = (unsigned short)k01;
            Pw[pl_idx(quad * 4 + 1, sub * 16 + l15)] = (unsigned short)(k01 >> 16);
            Pw[pl_idx(quad * 4 + 2, sub * 16 + l15)] = (unsigned short)k23;
            Pw[pl_idx(quad * 4 + 3, sub * 16 + l15)] = (unsigned short)(k23 >> 16);
        }
        asm volatile("s_waitcnt lgkmcnt(0)" ::: "memory");
        short8 pf0 = *(const short8*)&Pw[pl_idx(l15, quad * 8)];
        short8 pf1 = *(const short8*)&Pw[pl_idx(l15, 32 + quad * 8)];
#pragma unroll
        for (int g = 0; g < 4; ++g) {
            const float* vr = xb + (size_t)(g * 16 + l15) * TT + t0;
            float4 q0 = *(const float4*)(vr + quad * 8);
            float4 q1 = *(const float4*)(vr + quad * 8 + 4);
            float4 q2 = *(const float4*)(vr + 32 + quad * 8);
            float4 q3 = *(const float4*)(vr + 32 + quad * 8 + 4);
            short8 bv0 = cvt8(q0, q1);
            short8 bv1 = cvt8(q2, q3);
            oacc[g] = __builtin_amdgcn_mfma_f32_16x16x32_bf16(pf0, bv0, oacc[g], 0, 0, 0);
            oacc[g] = __builtin_amdgcn_mfma_f32_16x16x32_bf16(pf1, bv1, oacc[g], 0, 0, 0);
        }
    }

#pragma unroll
    for (int m = 1; m <= 8; m <<= 1) {
#pragma unroll
        for (int r = 0; r < 4; ++r) lsum[r] += __shfl_xor(lsum[r], m);
    }
    float gamma = gptr[0];
    float rl[4];
#pragma unroll
    for (int r = 0; r < 4; ++r) rl[r] = gamma / lsum[r];

    int ibase = i0 + wave * 16 + quad * 4;
#pragma unroll
    for (int g = 0; g < 4; ++g) {
        int c = g * 16 + l15;
        float4 xv = *(const float4*)(xb + (size_t)c * TT + ibase);
        float4 ov;
        ov.x = fmaf(oacc[g][0], rl[0], xv.x);
        ov.y = fmaf(oacc[g][1], rl[1], xv.y);
        ov.z = fmaf(oacc[g][2], rl[2], xv.z);
        ov.w = fmaf(oacc[g][3], rl[3], xv.w);
        *(float4*)(out + ((size_t)b * CHN + c) * TT + ibase) = ov;
    }
}

// ---------------------------------------------------------------------------
extern "C" void kernel_launch(void* const* d_in, const int* in_sizes, int n_in,
                              void* d_out, int out_size, void* d_ws, size_t ws_size,
                              hipStream_t stream) {
    const float* x  = (const float*)d_in[0];
    const float* w1 = (const float*)d_in[1];
    const float* w2 = (const float*)d_in[3];
    const float* gm = (const float*)d_in[5];
    float* out = (float*)d_out;

    const size_t XBYTES = (size_t)BB * CHN * TT * 2;   // 8 MB per bf16 copy
    if (ws_size >= 2 * XBYTES) {
        unsigned short* XtS = (unsigned short*)d_ws;
        unsigned short* XnS = (unsigned short*)((char*)d_ws + XBYTES);
        prep_kernel<<<BB * (TT / 64), 256, 0, stream>>>(x, XtS, XnS);
        attn_kernel<<<BB * (TT / 64), 256, 0, stream>>>(XtS, XnS, x, w1, w2, gm, out);
    } else {
        fused_attn_fallback<<<BB * (TT / 64), 256, 0, stream>>>(x, w1, w2, gm, out);
    }
}

// Round 12
// 162.540 us; speedup vs baseline: 2.6919x; 1.1983x over previous
//
#include <hip/hip_runtime.h>
#include <stdint.h>

// B=32, CH=64, T=2048. float32 in/out per the reference.
#define BB 32
#define CHN 64
#define TT 2048
#define LOG2E 1.4426950408889634f

typedef __attribute__((ext_vector_type(8))) short short8;
typedef __attribute__((ext_vector_type(4))) float f32x4;

#if defined(__has_builtin)
#if __has_builtin(__builtin_amdgcn_exp2f)
#define EXP2F __builtin_amdgcn_exp2f
#else
#define EXP2F exp2f
#endif
#else
#define EXP2F exp2f
#endif

#if defined(__has_builtin)
#if __has_builtin(__builtin_amdgcn_global_load_lds)
#define HAS_GLL 1
#endif
#endif

#ifdef HAS_GLL
typedef const __attribute__((address_space(1))) unsigned int* gas_t;
typedef __attribute__((address_space(3))) unsigned int* las_t;
__device__ __forceinline__ void async16(const void* g, void* l) {
    __builtin_amdgcn_global_load_lds((gas_t)g, (las_t)l, 16, 0, 0);
}
#endif

#define WAITALL asm volatile("s_waitcnt vmcnt(0) lgkmcnt(0)" ::: "memory")

// HW packed f32->bf16 (RNE), src0 -> low half, src1 -> high half.
__device__ __forceinline__ unsigned int pkbf(float a, float b) {
    unsigned int d;
    asm("v_cvt_pk_bf16_f32 %0, %1, %2" : "=v"(d) : "v"(a), "v"(b));
    return d;
}

__device__ __forceinline__ short8 cvt8(float4 q0, float4 q1) {
    union { unsigned int u[4]; short8 s; } v;
    v.u[0] = pkbf(q0.x, q0.y);
    v.u[1] = pkbf(q0.z, q0.w);
    v.u[2] = pkbf(q1.x, q1.y);
    v.u[3] = pkbf(q1.z, q1.w);
    return v.s;
}

// LDS tile element addressing: 64 rows x 8 segs of 8 shorts (16B).
// seg placement XOR-swizzled by row for conflict-light b128 reads.
#define XT_IDX(row, cseg) (((row) << 6) + ((((cseg) ^ ((row) & 7))) << 3))

// Transpose-staging swizzle for prep's LDS tile, element (t, c) -> short idx.
__device__ __forceinline__ int jt_idx(int t, int c) {
    int sw = ((t & 7) ^ ((t >> 3) & 7)) << 3;
    return t * 64 + (c ^ sw);
}

// Per-wave 16x64 P tile, (row=i-local, col=t-local) -> short idx.
__device__ __forceinline__ int pl_idx(int r, int c) {
    return r * 64 + (c ^ ((r & 7) << 3));
}

// ---------------------------------------------------------------------------
// Prep: one (b, 64-t chunk) per block.  Emits two pre-swizzled 8KB chunk
// tiles ready for linear global_load_lds staging + swizzled ds_read:
//   XtS[b][ch]: seg s=row*8+seg' holds Xt[t0+row][c=(seg'^(row&7))*8 ..+8]
//   XnS[b][ch]: seg s=row*8+seg' holds Xn[c=row][t0+(seg'^(row&7))*8 ..+8]
// Grid mapping b = blockIdx&31 keeps each batch's tiles on one XCD's L2.
// ---------------------------------------------------------------------------
__global__ __launch_bounds__(256) void prep_kernel(
        const float* __restrict__ x,
        unsigned short* __restrict__ XtS,
        unsigned short* __restrict__ XnS) {
    __shared__ unsigned short Jt[64 * 64];
    int tid = threadIdx.x;
    int b  = blockIdx.x & 31;
    int ch = blockIdx.x >> 5;
    int t0 = ch * 64;
    const float* xb = x + (size_t)b * CHN * TT;
    unsigned short* xt_blk = XtS + (size_t)(b * 32 + ch) * 4096;
    unsigned short* xn_blk = XnS + (size_t)(b * 32 + ch) * 4096;

    int p = tid >> 3;              // c rows 2p, 2p+1
    int tsub = (tid & 7) * 8;      // 8 t per thread
    int r0 = 2 * p, r1 = 2 * p + 1;
    const float* s0 = xb + (size_t)r0 * TT + t0 + tsub;
    const float* s1 = s0 + TT;
    float4 qa = *(const float4*)s0, qb = *(const float4*)(s0 + 4);
    float4 qc = *(const float4*)s1, qd = *(const float4*)(s1 + 4);
    short8 v0 = cvt8(qa, qb);
    short8 v1 = cvt8(qc, qd);

    // XnS segments (row = c, seg covers t tsub..+8)
    int seg = tsub >> 3;
    *(short8*)(xn_blk + ((size_t)(r0 * 8 + (seg ^ (r0 & 7)))) * 8) = v0;
    *(short8*)(xn_blk + ((size_t)(r1 * 8 + (seg ^ (r1 & 7)))) * 8) = v1;

    // transpose via LDS (packed c-pairs)
#pragma unroll
    for (int j = 0; j < 8; ++j) {
        int t = tsub + j;
        unsigned int pack = ((unsigned int)(unsigned short)v0[j]) |
                            (((unsigned int)(unsigned short)v1[j]) << 16);
        *(unsigned int*)&Jt[jt_idx(t, r0)] = pack;
    }
    __syncthreads();

    // XtS segments (row = t, seg covers 8 c)
    int t = tid >> 2, e = tid & 3;
#pragma unroll
    for (int k = 0; k < 2; ++k) {
        int cs = 2 * e + k;
        short8 vv = *(const short8*)&Jt[jt_idx(t, cs * 8)];
        *(short8*)(xt_blk + ((size_t)(t * 8 + (cs ^ (t & 7)))) * 8) = vv;
    }
}

// Stage one 8KB chunk tile: pure linear copy, wave w covers segs [w*128,+128).
__device__ __forceinline__ void stage8k(const unsigned short* __restrict__ g,
                                        unsigned short* l, int wave, int lane) {
#ifdef HAS_GLL
    const unsigned short* gs = g + (size_t)(wave * 128 + lane) * 8;
    unsigned short* ls = l + wave * 1024;
    async16(gs, ls);
    async16(gs + 512, ls + 512);
#else
    const short8* gs = (const short8*)g + (wave * 128 + lane);
    short8* ls = (short8*)l + (wave * 128 + lane);
    ls[0] = gs[0];
    ls[64] = gs[64];
#endif
}

// ---------------------------------------------------------------------------
// Attn: block = (b, 64 i-rows), b = blockIdx&31 (XCD affinity).
// Double-buffered global_load_lds staging (m97-style 2-barrier K-loop).
// Phase 1: Gram -> row min/max.  Phase 2: Gram -> exp2 -> P (LDS) -> PV.
// ---------------------------------------------------------------------------
__global__ __launch_bounds__(256) void attn_kernel(
        const unsigned short* __restrict__ XtS,
        const unsigned short* __restrict__ XnS,
        const float* __restrict__ x,
        const float* __restrict__ w1,
        const float* __restrict__ w2,
        const float* __restrict__ gptr,
        float* __restrict__ out) {
    __shared__ unsigned short Xt2[2][4096];   // 16 KB
    __shared__ unsigned short Xn2[2][4096];   // 16 KB
    __shared__ unsigned short Pl[4][1024];    // 8 KB, wave-private

    int tid  = threadIdx.x;
    int b    = blockIdx.x & 31;
    int iblk = blockIdx.x >> 5;
    int wave = tid >> 6, lane = tid & 63;
    int quad = lane >> 4, l15 = lane & 15;
    int i0 = iblk * 64;

    const unsigned short* XtB = XtS + (size_t)b * 32 * 4096;
    const unsigned short* XnB = XnS + (size_t)b * 32 * 4096;
    const float* xb = x + (size_t)b * CHN * TT;

    float s11 = 0.f;
#pragma unroll
    for (int h = 0; h < 8; ++h) s11 += w1[h] * w2[h];

    // ---- Phase 1 prologue: stage own i-chunk ----
    stage8k(XtB + (size_t)iblk * 4096, &Xt2[0][0], wave, lane);
    WAITALL;
    __syncthreads();

    int arow = wave * 16 + l15;
    short8 a0 = *(const short8*)&Xt2[0][XT_IDX(arow, quad)];
    short8 a1 = *(const short8*)&Xt2[0][XT_IDX(arow, quad + 4)];

    float vmin[4], vmax[4];
#pragma unroll
    for (int r = 0; r < 4; ++r) { vmin[r] = 3.4e38f; vmax[r] = -3.4e38f; }

    for (int m = 0; m < 32; ++m) {
        int buf = m & 1;
        if (m < 31)
            stage8k(XtB + (size_t)((iblk + m + 1) & 31) * 4096,
                    &Xt2[buf ^ 1][0], wave, lane);
        const unsigned short* tp = &Xt2[buf][0];
#pragma unroll
        for (int sub = 0; sub < 4; ++sub) {
            int row = sub * 16 + l15;
            short8 b0 = *(const short8*)&tp[XT_IDX(row, quad)];
            short8 b1 = *(const short8*)&tp[XT_IDX(row, quad + 4)];
            f32x4 acc = {0.f, 0.f, 0.f, 0.f};
            acc = __builtin_amdgcn_mfma_f32_16x16x32_bf16(a0, b0, acc, 0, 0, 0);
            acc = __builtin_amdgcn_mfma_f32_16x16x32_bf16(a1, b1, acc, 0, 0, 0);
#pragma unroll
            for (int r = 0; r < 4; ++r) {
                vmin[r] = fminf(vmin[r], acc[r]);
                vmax[r] = fmaxf(vmax[r], acc[r]);
            }
        }
        WAITALL;
        __syncthreads();
    }

    // ---- Phase transition: stage first phase-2 tiles while reducing ----
    stage8k(XtB, &Xt2[0][0], wave, lane);
    stage8k(XnB, &Xn2[0][0], wave, lane);

#pragma unroll
    for (int m = 1; m <= 8; m <<= 1) {
#pragma unroll
        for (int r = 0; r < 4; ++r) {
            vmin[r] = fminf(vmin[r], __shfl_xor(vmin[r], m));
            vmax[r] = fmaxf(vmax[r], __shfl_xor(vmax[r], m));
        }
    }
    float rdl2[4], mlog[4];
#pragma unroll
    for (int r = 0; r < 4; ++r) {
        float e0 = s11 * vmin[r], e1 = s11 * vmax[r];
        float mn = fminf(e0, e1), mx = fmaxf(e0, e1);
        float rd = LOG2E / (mx - mn + 1e-8f);
        rdl2[r] = s11 * rd;      // applied to raw Gram acc
        mlog[r] = mn * rd;
    }

    f32x4 oacc[4];
#pragma unroll
    for (int g = 0; g < 4; ++g) oacc[g] = (f32x4){0.f, 0.f, 0.f, 0.f};
    float lsum[4] = {0.f, 0.f, 0.f, 0.f};
    unsigned short* Pw = &Pl[wave][0];

    WAITALL;
    __syncthreads();

    // ---- Phase 2 ----
    for (int m = 0; m < 32; ++m) {
        int buf = m & 1;
        if (m < 31) {
            stage8k(XtB + (size_t)(m + 1) * 4096, &Xt2[buf ^ 1][0], wave, lane);
            stage8k(XnB + (size_t)(m + 1) * 4096, &Xn2[buf ^ 1][0], wave, lane);
        }
        const unsigned short* tp = &Xt2[buf][0];
        const unsigned short* xn = &Xn2[buf][0];
#pragma unroll
        for (int sub = 0; sub < 4; ++sub) {
            int row = sub * 16 + l15;
            short8 b0 = *(const short8*)&tp[XT_IDX(row, quad)];
            short8 b1 = *(const short8*)&tp[XT_IDX(row, quad + 4)];
            f32x4 acc = {0.f, 0.f, 0.f, 0.f};
            acc = __builtin_amdgcn_mfma_f32_16x16x32_bf16(a0, b0, acc, 0, 0, 0);
            acc = __builtin_amdgcn_mfma_f32_16x16x32_bf16(a1, b1, acc, 0, 0, 0);
            float pv0 = EXP2F(fmaf(acc[0], rdl2[0], -mlog[0]));
            float pv1 = EXP2F(fmaf(acc[1], rdl2[1], -mlog[1]));
            float pv2 = EXP2F(fmaf(acc[2], rdl2[2], -mlog[2]));
            float pv3 = EXP2F(fmaf(acc[3], rdl2[3], -mlog[3]));
            lsum[0] += pv0; lsum[1] += pv1; lsum[2] += pv2; lsum[3] += pv3;
            unsigned int k01 = pkbf(pv0, pv1);
            unsigned int k23 = pkbf(pv2, pv3);
            Pw[pl_idx(quad * 4 + 0, sub * 16 + l15)] = (unsigned short)k01;
            Pw[pl_idx(quad * 4 + 1, sub * 16 + l15)] = (unsigned short)(k01 >> 16);
            Pw[pl_idx(quad * 4 + 2, sub * 16 + l15)] = (unsigned short)k23;
            Pw[pl_idx(quad * 4 + 3, sub * 16 + l15)] = (unsigned short)(k23 >> 16);
        }
        // own-wave DS ordering: P writes retire before P reads issue results
        asm volatile("s_waitcnt lgkmcnt(0)" ::: "memory");
        short8 pf0 = *(const short8*)&Pw[pl_idx(l15, quad * 8)];
        short8 pf1 = *(const short8*)&Pw[pl_idx(l15, 32 + quad * 8)];
#pragma unroll
        for (int g = 0; g < 4; ++g) {
            int row = g * 16 + l15;
            short8 bv0 = *(const short8*)&xn[XT_IDX(row, quad)];
            short8 bv1 = *(const short8*)&xn[XT_IDX(row, quad + 4)];
            oacc[g] = __builtin_amdgcn_mfma_f32_16x16x32_bf16(pf0, bv0, oacc[g], 0, 0, 0);
            oacc[g] = __builtin_amdgcn_mfma_f32_16x16x32_bf16(pf1, bv1, oacc[g], 0, 0, 0);
        }
        WAITALL;
        __syncthreads();
    }

    // ---- Epilogue ----
#pragma unroll
    for (int m = 1; m <= 8; m <<= 1) {
#pragma unroll
        for (int r = 0; r < 4; ++r) lsum[r] += __shfl_xor(lsum[r], m);
    }
    float gamma = gptr[0];
    float rl[4];
#pragma unroll
    for (int r = 0; r < 4; ++r) rl[r] = gamma / lsum[r];

    int ibase = i0 + wave * 16 + quad * 4;
#pragma unroll
    for (int g = 0; g < 4; ++g) {
        int c = g * 16 + l15;
        float4 xv = *(const float4*)(xb + (size_t)c * TT + ibase);
        float4 ov;
        ov.x = fmaf(oacc[g][0], rl[0], xv.x);
        ov.y = fmaf(oacc[g][1], rl[1], xv.y);
        ov.z = fmaf(oacc[g][2], rl[2], xv.z);
        ov.w = fmaf(oacc[g][3], rl[3], xv.w);
        *(float4*)(out + ((size_t)b * CHN + c) * TT + ibase) = ov;
    }
}

// ---------------------------------------------------------------------------
// Fallback (round-3 structure, zero workspace) — only if ws < 16 MB.
// ---------------------------------------------------------------------------
__device__ __forceinline__ void stage_tile_fb(const float* __restrict__ xb,
                                              int tbase, unsigned short* Jt, int tid) {
    int p = tid >> 3;
    int tsub = (tid & 7) * 8;
    const float* s0 = xb + (size_t)(2 * p) * TT + tbase + tsub;
    const float* s1 = s0 + TT;
    float4 a0 = *(const float4*)s0;
    float4 a1 = *(const float4*)(s0 + 4);
    float4 b0 = *(const float4*)s1;
    float4 b1 = *(const float4*)(s1 + 4);
    short8 v0 = cvt8(a0, a1);
    short8 v1 = cvt8(b0, b1);
#pragma unroll
    for (int j = 0; j < 8; ++j) {
        int t = tsub + j;
        unsigned int pack = ((unsigned int)(unsigned short)v0[j]) |
                            (((unsigned int)(unsigned short)v1[j]) << 16);
        *(unsigned int*)&Jt[jt_idx(t, 2 * p)] = pack;
    }
}

__global__ __launch_bounds__(256) void fused_attn_fallback(
        const float* __restrict__ x,
        const float* __restrict__ w1,
        const float* __restrict__ w2,
        const float* __restrict__ gptr,
        float* __restrict__ out) {
    __shared__ unsigned short Jt[64 * 64];
    __shared__ unsigned short Pl[4][16 * 64];

    int tid  = threadIdx.x;
    int b    = blockIdx.x >> 5;
    int iblk = blockIdx.x & 31;
    int wave = tid >> 6;
    int lane = tid & 63;
    int quad = lane >> 4, l15 = lane & 15;
    int i0 = iblk * 64;
    const float* xb = x + (size_t)b * CHN * TT;

    float s11 = 0.f;
#pragma unroll
    for (int h = 0; h < 8; ++h) s11 += w1[h] * w2[h];

    stage_tile_fb(xb, i0, Jt, tid);
    __syncthreads();
    short8 a0 = *(const short8*)&Jt[jt_idx(wave * 16 + l15, quad * 8)];
    short8 a1 = *(const short8*)&Jt[jt_idx(wave * 16 + l15, 32 + quad * 8)];

    float vmin[4], vmax[4];
#pragma unroll
    for (int r = 0; r < 4; ++r) { vmin[r] = 3.4e38f; vmax[r] = -3.4e38f; }

    for (int t0 = 0; t0 < TT; t0 += 64) {
        __syncthreads();
        stage_tile_fb(xb, t0, Jt, tid);
        __syncthreads();
#pragma unroll
        for (int sub = 0; sub < 4; ++sub) {
            short8 b0 = *(const short8*)&Jt[jt_idx(sub * 16 + l15, quad * 8)];
            short8 b1 = *(const short8*)&Jt[jt_idx(sub * 16 + l15, 32 + quad * 8)];
            f32x4 acc = {0.f, 0.f, 0.f, 0.f};
            acc = __builtin_amdgcn_mfma_f32_16x16x32_bf16(a0, b0, acc, 0, 0, 0);
            acc = __builtin_amdgcn_mfma_f32_16x16x32_bf16(a1, b1, acc, 0, 0, 0);
#pragma unroll
            for (int r = 0; r < 4; ++r) {
                vmin[r] = fminf(vmin[r], acc[r]);
                vmax[r] = fmaxf(vmax[r], acc[r]);
            }
        }
    }
#pragma unroll
    for (int m = 1; m <= 8; m <<= 1) {
#pragma unroll
        for (int r = 0; r < 4; ++r) {
            vmin[r] = fminf(vmin[r], __shfl_xor(vmin[r], m));
            vmax[r] = fmaxf(vmax[r], __shfl_xor(vmax[r], m));
        }
    }
    float rdl2[4], mlog[4];
#pragma unroll
    for (int r = 0; r < 4; ++r) {
        float e0 = s11 * vmin[r], e1 = s11 * vmax[r];
        float mn = fminf(e0, e1), mx = fmaxf(e0, e1);
        float rd = LOG2E / (mx - mn + 1e-8f);
        rdl2[r] = s11 * rd;
        mlog[r] = mn * rd;
    }

    f32x4 oacc[4];
#pragma unroll
    for (int g = 0; g < 4; ++g) oacc[g] = (f32x4){0.f, 0.f, 0.f, 0.f};
    float lsum[4] = {0.f, 0.f, 0.f, 0.f};
    unsigned short* Pw = &Pl[wave][0];

    for (int t0 = 0; t0 < TT; t0 += 64) {
        __syncthreads();
        stage_tile_fb(xb, t0, Jt, tid);
        __syncthreads();
#pragma unroll
        for (int sub = 0; sub < 4; ++sub) {
            short8 b0 = *(const short8*)&Jt[jt_idx(sub * 16 + l15, quad * 8)];
            short8 b1 = *(const short8*)&Jt[jt_idx(sub * 16 + l15, 32 + quad * 8)];
            f32x4 acc = {0.f, 0.f, 0.f, 0.f};
            acc = __builtin_amdgcn_mfma_f32_16x16x32_bf16(a0, b0, acc, 0, 0, 0);
            acc = __builtin_amdgcn_mfma_f32_16x16x32_bf16(a1, b1, acc, 0, 0, 0);
            float pv0 = EXP2F(fmaf(acc[0], rdl2[0], -mlog[0]));
            float pv1 = EXP2F(fmaf(acc[1], rdl2[1], -mlog[1]));
            float pv2 = EXP2F(fmaf(acc[2], rdl2[2], -mlog[2]));
            float pv3 = EXP2F(fmaf(acc[3], rdl2[3], -mlog[3]));
            lsum[0] += pv0; lsum[1] += pv1; lsum[2] += pv2; lsum[3] += pv3;
            unsigned int k01 = pkbf(pv0, pv1);
            unsigned int k23 = pkbf(pv2, pv3);
            Pw[pl_idx(quad * 4 + 0, sub * 16 + l15)] = (unsigned short)k01;
            Pw[pl_idx(quad * 4 + 1, sub * 16 + l15)] = (unsigned short)(k01 >> 16);
            Pw[pl_idx(quad * 4 + 2, sub * 16 + l15)] = (unsigned short)k23;
            Pw[pl_idx(quad * 4 + 3, sub * 16 + l15)] = (unsigned short)(k23 >> 16);
        }
        asm volatile("s_waitcnt lgkmcnt(0)" ::: "memory");
        short8 pf0 = *(const short8*)&Pw[pl_idx(l15, quad * 8)];
        short8 pf1 = *(const short8*)&Pw[pl_idx(l15, 32 + quad * 8)];
#pragma unroll
        for (int g = 0; g < 4; ++g) {
            const float* vr = xb + (size_t)(g * 16 + l15) * TT + t0;
            float4 q0 = *(const float4*)(vr + quad * 8);
            float4 q1 = *(const float4*)(vr + quad * 8 + 4);
            float4 q2 = *(const float4*)(vr + 32 + quad * 8);
            float4 q3 = *(const float4*)(vr + 32 + quad * 8 + 4);
            short8 bv0 = cvt8(q0, q1);
            short8 bv1 = cvt8(q2, q3);
            oacc[g] = __builtin_amdgcn_mfma_f32_16x16x32_bf16(pf0, bv0, oacc[g], 0, 0, 0);
            oacc[g] = __builtin_amdgcn_mfma_f32_16x16x32_bf16(pf1, bv1, oacc[g], 0, 0, 0);
        }
    }

#pragma unroll
    for (int m = 1; m <= 8; m <<= 1) {
#pragma unroll
        for (int r = 0; r < 4; ++r) lsum[r] += __shfl_xor(lsum[r], m);
    }
    float gamma = gptr[0];
    float rl[4];
#pragma unroll
    for (int r = 0; r < 4; ++r) rl[r] = gamma / lsum[r];

    int ibase = i0 + wave * 16 + quad * 4;
#pragma unroll
    for (int g = 0; g < 4; ++g) {
        int c = g * 16 + l15;
        float4 xv = *(const float4*)(xb + (size_t)c * TT + ibase);
        float4 ov;
        ov.x = fmaf(oacc[g][0], rl[0], xv.x);
        ov.y = fmaf(oacc[g][1], rl[1], xv.y);
        ov.z = fmaf(oacc[g][2], rl[2], xv.z);
        ov.w = fmaf(oacc[g][3], rl[3], xv.w);
        *(float4*)(out + ((size_t)b * CHN + c) * TT + ibase) = ov;
    }
}

// ---------------------------------------------------------------------------
extern "C" void kernel_launch(void* const* d_in, const int* in_sizes, int n_in,
                              void* d_out, int out_size, void* d_ws, size_t ws_size,
                              hipStream_t stream) {
    const float* x  = (const float*)d_in[0];
    const float* w1 = (const float*)d_in[1];
    const float* w2 = (const float*)d_in[3];
    const float* gm = (const float*)d_in[5];
    float* out = (float*)d_out;

    const size_t XBYTES = (size_t)BB * CHN * TT * 2;   // 8 MB per bf16 copy
    if (ws_size >= 2 * XBYTES) {
        unsigned short* XtS = (unsigned short*)d_ws;
        unsigned short* XnS = (unsigned short*)((char*)d_ws + XBYTES);
        prep_kernel<<<BB * (TT / 64), 256, 0, stream>>>(x, XtS, XnS);
        attn_kernel<<<BB * (TT / 64), 256, 0, stream>>>(XtS, XnS, x, w1, w2, gm, out);
    } else {
        fused_attn_fallback<<<BB * (TT / 64), 256, 0, stream>>>(x, w1, w2, gm, out);
    }
}